// Round 4
// baseline (243.070 us; speedup 1.0000x reference)
//
#include <hip/hip_runtime.h>

typedef __bf16 bf16;
typedef bf16 bf16x8 __attribute__((ext_vector_type(8)));
typedef bf16 bf16x4 __attribute__((ext_vector_type(4)));
typedef float f32x4 __attribute__((ext_vector_type(4)));

#define MFMA16(a, b, c) __builtin_amdgcn_mfma_f32_16x16x32_bf16(a, b, c, 0, 0, 0)
// wait lgkmcnt(0) only (vmcnt=0x3f, expcnt=7): per-wave LDS drain, no global drain
#define WAIT_LDS() __builtin_amdgcn_s_waitcnt(0xC07F)

// ---------------- merged prep kernel ----------------
__global__ void k_prep(const float* __restrict__ x, const float* __restrict__ Wq,
                       const float* __restrict__ Wkv, const float* __restrict__ Wo,
                       const float* __restrict__ srw,
                       bf16* __restrict__ x_bf, bf16* __restrict__ WqT,
                       bf16* __restrict__ WkvT, bf16* __restrict__ WoT,
                       bf16* __restrict__ srwT) {
  int bid = blockIdx.x, tid = threadIdx.x;
  if (bid < 8192) {
    int i = (bid * 256 + tid) * 4;
    float4 v = *(const float4*)(x + i);
    bf16x4 o;
    o[0] = (bf16)v.x; o[1] = (bf16)v.y; o[2] = (bf16)v.z; o[3] = (bf16)v.w;
    *(bf16x4*)(x_bf + i) = o;
  } else if (bid < 9216) {
    int id = (bid - 8192) * 256 + tid;  // 0..262143
    if (id < 65536) {                   // WqT
      int c = id >> 8, r = id & 255;
      WqT[id] = (bf16)Wq[r * 256 + c];
    } else if (id < 196608) {           // WkvT
      int l = id - 65536;
      int c = l >> 8, r = l & 255;
      WkvT[l] = (bf16)Wkv[r * 512 + c];
    } else {                            // WoT
      int l = id - 196608;
      int c = l >> 8, r = l & 255;
      WoT[l] = (bf16)Wo[r * 256 + c];
    }
  } else {
    int id4 = ((bid - 9216) * 256 + tid) * 4;  // input-linear o*4096+i*16+p
    int o = id4 >> 12, rem = id4 & 4095;
    int i = rem >> 4, p = rem & 15;
    float4 v = *(const float4*)(srw + id4);
    srwT[(o << 12) + ((p + 0) << 8) + i] = (bf16)v.x;
    srwT[(o << 12) + ((p + 1) << 8) + i] = (bf16)v.y;
    srwT[(o << 12) + ((p + 2) << 8) + i] = (bf16)v.z;
    srwT[(o << 12) + ((p + 3) << 8) + i] = (bf16)v.w;
  }
}

// ---------------- generic MFMA GEMM (conv / KV / out) ----------------
template <int AMODE, int EMODE>
__global__ __launch_bounds__(256, 2) void k_gemm(
    const bf16* __restrict__ A, const bf16* __restrict__ Bt,
    void* __restrict__ Cout, const float* __restrict__ bias,
    int M, int N, int K) {
  constexpr int LDT = 72;
  __shared__ alignas(16) bf16 As[64 * LDT];
  __shared__ alignas(16) bf16 Bs[64 * LDT];
  int tid = threadIdx.x;
  int m0 = blockIdx.x * 64, n0 = blockIdx.y * 64;
  int kbeg = blockIdx.z * K;
  int wave = tid >> 6, lane = tid & 63;
  int quad = lane >> 4, l16 = lane & 15;

  f32x4 acc[4];
#pragma unroll
  for (int i = 0; i < 4; i++) acc[i] = (f32x4){0.f, 0.f, 0.f, 0.f};

  for (int k0 = kbeg; k0 < kbeg + K; k0 += 64) {
#pragma unroll
    for (int t = 0; t < 2; t++) {
      int c = tid + t * 256;
      int row = c >> 3, c8 = (c & 7) * 8;
      const bf16* asrc;
      if constexpr (AMODE == 0) {
        asrc = A + (size_t)(m0 + row) * K + k0 + c8;
      } else {
        int m = m0 + row;
        int b = m >> 8, tt = m & 255;
        int oh = tt >> 4, ow = tt & 15;
        int p = k0 >> 8;
        int kh = p >> 2, kw = p & 3;
        int tok = (oh * 4 + kh) * 64 + ow * 4 + kw;
        asrc = A + ((size_t)(b * 4096 + tok) << 8) + (k0 & 255) + c8;
      }
      *(bf16x8*)&As[row * LDT + c8] = *(const bf16x8*)asrc;
      *(bf16x8*)&Bs[row * LDT + c8] =
          *(const bf16x8*)(Bt + (size_t)(n0 + row) * ((AMODE == 1) ? 4096 : K) + k0 + c8);
    }
    __syncthreads();
#pragma unroll
    for (int kk = 0; kk < 64; kk += 32) {
      bf16x8 af = *(const bf16x8*)&As[(wave * 16 + l16) * LDT + kk + quad * 8];
#pragma unroll
      for (int nt = 0; nt < 4; nt++) {
        bf16x8 bfr = *(const bf16x8*)&Bs[(nt * 16 + l16) * LDT + kk + quad * 8];
        acc[nt] = MFMA16(af, bfr, acc[nt]);
      }
    }
    __syncthreads();
  }

  int rbase = m0 + wave * 16 + quad * 4;
#pragma unroll
  for (int nt = 0; nt < 4; nt++) {
    int col = n0 + nt * 16 + l16;
#pragma unroll
    for (int r = 0; r < 4; r++) {
      float v = acc[nt][r];
      int row = rbase + r;
      if constexpr (EMODE == 2) {
        int b = row >> 8, key = row & 255;
        int isv = col >> 8, c2 = col & 255;
        int hh = c2 >> 6, d = c2 & 63;
        int bh = b * 4 + hh;
        bf16* dst = (bf16*)Cout;
        if (isv == 0)
          dst[(((size_t)bh) * 256 + key) * 64 + d] = (bf16)v;                  // K [bh][key][d]
        else
          dst[32 * 256 * 64 + (((size_t)bh) * 64 + d) * 256 + key] = (bf16)v;  // V^T [bh][d][key]
      } else if constexpr (EMODE == 3) {
        ((float*)Cout)[(size_t)row * N + col] = v + bias[col];
      } else {  // EMODE 4
        ((float*)Cout)[((size_t)blockIdx.z * M + row) * N + col] = v;
      }
    }
  }
}

// ---------------- LayerNorm (sum of 8 fp32 partials + sr_b -> bf16) ----------------
__global__ void k_ln(const float* __restrict__ part, const float* __restrict__ srb,
                     const float* __restrict__ g, const float* __restrict__ bb,
                     bf16* __restrict__ out) {
  int row = blockIdx.x * 4 + (threadIdx.x >> 6);
  int lane = threadIdx.x & 63;
  size_t off = (size_t)row * 256 + lane * 4;
  float4 v = *(const float4*)&part[off];
#pragma unroll
  for (int z = 1; z < 8; z++) {
    float4 p = *(const float4*)&part[(size_t)z * 2048 * 256 + off];
    v.x += p.x; v.y += p.y; v.z += p.z; v.w += p.w;
  }
  int c = lane * 4;
  v.x += srb[c + 0]; v.y += srb[c + 1]; v.z += srb[c + 2]; v.w += srb[c + 3];
  float s = v.x + v.y + v.z + v.w;
#pragma unroll
  for (int i = 1; i < 64; i <<= 1) s += __shfl_xor(s, i, 64);
  float mu = s * (1.f / 256.f);
  float d0 = v.x - mu, d1 = v.y - mu, d2 = v.z - mu, d3 = v.w - mu;
  float q = d0 * d0 + d1 * d1 + d2 * d2 + d3 * d3;
#pragma unroll
  for (int i = 1; i < 64; i <<= 1) q += __shfl_xor(q, i, 64);
  float rs = rsqrtf(q * (1.f / 256.f) + 1e-5f);
  bf16x4 o;
  o[0] = (bf16)(d0 * rs * g[c + 0] + bb[c + 0]);
  o[1] = (bf16)(d1 * rs * g[c + 1] + bb[c + 1]);
  o[2] = (bf16)(d2 * rs * g[c + 2] + bb[c + 2]);
  o[3] = (bf16)(d3 * rs * g[c + 3] + bb[c + 3]);
  *(bf16x4*)&out[(size_t)row * 256 + c] = o;
}

// ---------------- attention, barrier-free, fused Q-proj ----------------
// grid (32 bh, 64 qtiles), block 256 = 4 independent waves (16 q-rows each).
// All MFMA operand fragments (x, Wq, K, V) load directly from global (L1/L2-hot).
// LDS: one [64][264] buffer; wave w uses only rows [w*16, w*16+16) for the
// Q and P C->A layout round-trips -> wave-local -> NO __syncthreads anywhere.
__global__ __launch_bounds__(256, 4) void k_attn(
    const bf16* __restrict__ xbf,  // [B*4096][256]
    const bf16* __restrict__ WqT,  // [256 out][256 in]
    const bf16* __restrict__ Kb,   // [32][256][64]
    const bf16* __restrict__ Vt_g, // [32][64][256]  (V^T)
    bf16* __restrict__ O) {        // [B*4096][256]
  constexpr int LDP = 264;  // bf16 stride, 16B-aligned rows
  int bh = blockIdx.x, qt = blockIdx.y;
  int b = bh >> 2, h = bh & 3;
  int tid = threadIdx.x, wave = tid >> 6, lane = tid & 63;
  int quad = lane >> 4, l16 = lane & 15;

  __shared__ alignas(16) bf16 Ps[64 * LDP];

  const bf16* xrow  = xbf + ((size_t)(b * 4096 + qt * 64 + wave * 16 + l16) << 8) + quad * 8;
  const bf16* wqrow = WqT + ((size_t)(h * 64) << 8);
  const bf16* Kbh   = Kb + (size_t)bh * 256 * 64;
  const bf16* Vbh   = Vt_g + (size_t)bh * 64 * 256;

  // ---- phase 1: Q = x @ Wq_head (fragments straight from global) ----
  f32x4 q[4];
#pragma unroll
  for (int i = 0; i < 4; i++) q[i] = (f32x4){0.f, 0.f, 0.f, 0.f};
#pragma unroll
  for (int k0 = 0; k0 < 256; k0 += 32) {
    bf16x8 ax = *(const bf16x8*)(xrow + k0);
#pragma unroll
    for (int nt = 0; nt < 4; nt++) {
      bf16x8 bw = *(const bf16x8*)&wqrow[((size_t)(nt * 16 + l16) << 8) + k0 + quad * 8];
      q[nt] = MFMA16(ax, bw, q[nt]);
    }
  }

  // Q C-layout -> wave-local LDS stripe (row-major [q][d], stride LDP)
#pragma unroll
  for (int nt = 0; nt < 4; nt++)
#pragma unroll
    for (int r = 0; r < 4; r++)
      Ps[(wave * 16 + quad * 4 + r) * LDP + nt * 16 + l16] = (bf16)q[nt][r];
  WAIT_LDS();
  bf16x8 aq0 = *(const bf16x8*)&Ps[(wave * 16 + l16) * LDP + 0 + quad * 8];
  bf16x8 aq1 = *(const bf16x8*)&Ps[(wave * 16 + l16) * LDP + 32 + quad * 8];

  // ---- phase 2: S = Q K^T (K fragments from global) ----
  f32x4 s[16];
#pragma unroll
  for (int i = 0; i < 16; i++) s[i] = (f32x4){0.f, 0.f, 0.f, 0.f};
#pragma unroll
  for (int nt = 0; nt < 16; nt++) {
    bf16x8 b0 = *(const bf16x8*)&Kbh[(nt * 16 + l16) * 64 + 0 + quad * 8];
    bf16x8 b1 = *(const bf16x8*)&Kbh[(nt * 16 + l16) * 64 + 32 + quad * 8];
    s[nt] = MFMA16(aq0, b0, s[nt]);
    s[nt] = MFMA16(aq1, b1, s[nt]);
  }

  // softmax over 256 keys; lane holds rows quad*4+r, col l16 of each 16-tile
  const float scale = 0.125f;
#pragma unroll
  for (int r = 0; r < 4; r++) {
    float m = -1e30f;
#pragma unroll
    for (int nt = 0; nt < 16; nt++) m = fmaxf(m, s[nt][r]);
#pragma unroll
    for (int i = 1; i < 16; i <<= 1) m = fmaxf(m, __shfl_xor(m, i, 64));
    float sum = 0.f;
#pragma unroll
    for (int nt = 0; nt < 16; nt++) {
      float e = __expf((s[nt][r] - m) * scale);
      s[nt][r] = e;
      sum += e;
    }
#pragma unroll
    for (int i = 1; i < 16; i <<= 1) sum += __shfl_xor(sum, i, 64);
    float inv = 1.f / sum;
#pragma unroll
    for (int nt = 0; nt < 16; nt++) s[nt][r] *= inv;
  }

  // P C-layout -> same wave-local LDS stripe (overwrites Q; Q already in regs)
#pragma unroll
  for (int nt = 0; nt < 16; nt++)
#pragma unroll
    for (int r = 0; r < 4; r++)
      Ps[(wave * 16 + quad * 4 + r) * LDP + nt * 16 + l16] = (bf16)s[nt][r];
  WAIT_LDS();

  // ---- phase 3: O = P V (V^T fragments from global) ----
  f32x4 o[4];
#pragma unroll
  for (int i = 0; i < 4; i++) o[i] = (f32x4){0.f, 0.f, 0.f, 0.f};
#pragma unroll
  for (int k0 = 0; k0 < 256; k0 += 32) {
    bf16x8 ap = *(const bf16x8*)&Ps[(wave * 16 + l16) * LDP + k0 + quad * 8];
#pragma unroll
    for (int nt = 0; nt < 4; nt++) {
      bf16x8 bv = *(const bf16x8*)&Vbh[(nt * 16 + l16) * 256 + k0 + quad * 8];
      o[nt] = MFMA16(ap, bv, o[nt]);
    }
  }

  size_t orow = (size_t)b * 4096 + qt * 64 + wave * 16 + quad * 4;
#pragma unroll
  for (int nt = 0; nt < 4; nt++) {
    int col = h * 64 + nt * 16 + l16;
#pragma unroll
    for (int r = 0; r < 4; r++) O[(orow + r) * 256 + col] = (bf16)o[nt][r];
  }
}

// ---------------- launch ----------------
extern "C" void kernel_launch(void* const* d_in, const int* in_sizes, int n_in,
                              void* d_out, int out_size, void* d_ws, size_t ws_size,
                              hipStream_t stream) {
  (void)in_sizes; (void)n_in; (void)out_size; (void)ws_size;
  const float* x   = (const float*)d_in[0];
  const float* Wq  = (const float*)d_in[3];
  const float* Wkv = (const float*)d_in[4];
  const float* srw = (const float*)d_in[5];
  const float* srb = (const float*)d_in[6];
  const float* lng = (const float*)d_in[7];
  const float* lnb = (const float*)d_in[8];
  const float* Wo  = (const float*)d_in[9];
  const float* bo  = (const float*)d_in[10];
  float* out = (float*)d_out;

  char* ws = (char*)d_ws;
  bf16*  x_bf  = (bf16*)(ws + 0);          // 16,777,216 B
  bf16*  AObuf = (bf16*)(ws + 16777216);   // 16,777,216
  float* convp = (float*)(ws + 33554432);  // 16,777,216 (8 partials)
  bf16*  WqT   = (bf16*)(ws + 50331648);   //    131,072
  bf16*  WkvT  = (bf16*)(ws + 50462720);   //    262,144
  bf16*  WoT   = (bf16*)(ws + 50724864);   //    131,072
  bf16*  srwT  = (bf16*)(ws + 50855936);   //  2,097,152
  bf16*  xln   = (bf16*)(ws + 52953088);   //  1,048,576
  bf16*  kvbuf = (bf16*)(ws + 54001664);   //  2,097,152 (K then V^T)

  k_prep<<<10240, 256, 0, stream>>>(x, Wq, Wkv, Wo, srw, x_bf, WqT, WkvT, WoT, srwT);
  // conv (im2col GEMM), split-K 8x512 -> fp32 partials [8][2048][256]
  k_gemm<1, 4><<<dim3(32, 4, 8), 256, 0, stream>>>(x_bf, srwT, convp, nullptr, 2048, 256, 512);
  // LayerNorm (+partial reduce +sr_b) -> bf16 [2048][256]
  k_ln<<<512, 256, 0, stream>>>(convp, srb, lng, lnb, xln);
  // KV = xln @ Wkv -> K [32][256][64], V^T [32][64][256] bf16
  k_gemm<0, 2><<<dim3(32, 8), 256, 0, stream>>>(xln, WkvT, kvbuf, nullptr, 2048, 512, 256);
  // attention (Q-proj fused, barrier-free)
  k_attn<<<dim3(32, 64), 256, 0, stream>>>(x_bf, WqT, kvbuf, kvbuf + (size_t)32 * 256 * 64, AObuf);
  // out = AO @ Wo + bo -> fp32 d_out
  k_gemm<0, 3><<<dim3(512, 4), 256, 0, stream>>>(AObuf, WoT, out, bo, 32768, 256, 256);
}

// Round 5
// 219.047 us; speedup vs baseline: 1.1097x; 1.1097x over previous
//
#include <hip/hip_runtime.h>

typedef __bf16 bf16;
typedef bf16 bf16x8 __attribute__((ext_vector_type(8)));
typedef bf16 bf16x4 __attribute__((ext_vector_type(4)));
typedef float f32x4 __attribute__((ext_vector_type(4)));

#define MFMA16(a, b, c) __builtin_amdgcn_mfma_f32_16x16x32_bf16(a, b, c, 0, 0, 0)
// wait lgkmcnt(0) only (vmcnt=0x3f, expcnt=7): per-wave LDS drain, no global drain
#define WAIT_LDS() __builtin_amdgcn_s_waitcnt(0xC07F)

// ---------------- merged prep kernel ----------------
__global__ void k_prep(const float* __restrict__ x, const float* __restrict__ Wq,
                       const float* __restrict__ Wkv, const float* __restrict__ Wo,
                       const float* __restrict__ srw,
                       bf16* __restrict__ x_bf, bf16* __restrict__ WqT,
                       bf16* __restrict__ WkvT, bf16* __restrict__ WoT,
                       bf16* __restrict__ srwT) {
  int bid = blockIdx.x, tid = threadIdx.x;
  if (bid < 8192) {
    int i = (bid * 256 + tid) * 4;
    float4 v = *(const float4*)(x + i);
    bf16x4 o;
    o[0] = (bf16)v.x; o[1] = (bf16)v.y; o[2] = (bf16)v.z; o[3] = (bf16)v.w;
    *(bf16x4*)(x_bf + i) = o;
  } else if (bid < 9216) {
    int id = (bid - 8192) * 256 + tid;  // 0..262143
    if (id < 65536) {                   // WqT
      int c = id >> 8, r = id & 255;
      WqT[id] = (bf16)Wq[r * 256 + c];
    } else if (id < 196608) {           // WkvT
      int l = id - 65536;
      int c = l >> 8, r = l & 255;
      WkvT[l] = (bf16)Wkv[r * 512 + c];
    } else {                            // WoT
      int l = id - 196608;
      int c = l >> 8, r = l & 255;
      WoT[l] = (bf16)Wo[r * 256 + c];
    }
  } else {
    int id4 = ((bid - 9216) * 256 + tid) * 4;  // input-linear o*4096+i*16+p
    int o = id4 >> 12, rem = id4 & 4095;
    int i = rem >> 4, p = rem & 15;
    float4 v = *(const float4*)(srw + id4);
    srwT[(o << 12) + ((p + 0) << 8) + i] = (bf16)v.x;
    srwT[(o << 12) + ((p + 1) << 8) + i] = (bf16)v.y;
    srwT[(o << 12) + ((p + 2) << 8) + i] = (bf16)v.z;
    srwT[(o << 12) + ((p + 3) << 8) + i] = (bf16)v.w;
  }
}

// ---------------- generic MFMA GEMM (conv / KV / out) ----------------
template <int AMODE, int EMODE>
__global__ __launch_bounds__(256, 2) void k_gemm(
    const bf16* __restrict__ A, const bf16* __restrict__ Bt,
    void* __restrict__ Cout, const float* __restrict__ bias,
    int M, int N, int K) {
  constexpr int LDT = 72;
  __shared__ alignas(16) bf16 As[64 * LDT];
  __shared__ alignas(16) bf16 Bs[64 * LDT];
  int tid = threadIdx.x;
  int m0 = blockIdx.x * 64, n0 = blockIdx.y * 64;
  int kbeg = blockIdx.z * K;
  int wave = tid >> 6, lane = tid & 63;
  int quad = lane >> 4, l16 = lane & 15;

  f32x4 acc[4];
#pragma unroll
  for (int i = 0; i < 4; i++) acc[i] = (f32x4){0.f, 0.f, 0.f, 0.f};

  for (int k0 = kbeg; k0 < kbeg + K; k0 += 64) {
#pragma unroll
    for (int t = 0; t < 2; t++) {
      int c = tid + t * 256;
      int row = c >> 3, c8 = (c & 7) * 8;
      const bf16* asrc;
      if constexpr (AMODE == 0) {
        asrc = A + (size_t)(m0 + row) * K + k0 + c8;
      } else {
        int m = m0 + row;
        int b = m >> 8, tt = m & 255;
        int oh = tt >> 4, ow = tt & 15;
        int p = k0 >> 8;
        int kh = p >> 2, kw = p & 3;
        int tok = (oh * 4 + kh) * 64 + ow * 4 + kw;
        asrc = A + ((size_t)(b * 4096 + tok) << 8) + (k0 & 255) + c8;
      }
      *(bf16x8*)&As[row * LDT + c8] = *(const bf16x8*)asrc;
      *(bf16x8*)&Bs[row * LDT + c8] =
          *(const bf16x8*)(Bt + (size_t)(n0 + row) * ((AMODE == 1) ? 4096 : K) + k0 + c8);
    }
    __syncthreads();
#pragma unroll
    for (int kk = 0; kk < 64; kk += 32) {
      bf16x8 af = *(const bf16x8*)&As[(wave * 16 + l16) * LDT + kk + quad * 8];
#pragma unroll
      for (int nt = 0; nt < 4; nt++) {
        bf16x8 bfr = *(const bf16x8*)&Bs[(nt * 16 + l16) * LDT + kk + quad * 8];
        acc[nt] = MFMA16(af, bfr, acc[nt]);
      }
    }
    __syncthreads();
  }

  int rbase = m0 + wave * 16 + quad * 4;
#pragma unroll
  for (int nt = 0; nt < 4; nt++) {
    int col = n0 + nt * 16 + l16;
#pragma unroll
    for (int r = 0; r < 4; r++) {
      float v = acc[nt][r];
      int row = rbase + r;
      if constexpr (EMODE == 2) {
        int b = row >> 8, key = row & 255;
        int isv = col >> 8, c2 = col & 255;
        int hh = c2 >> 6, d = c2 & 63;
        int bh = b * 4 + hh;
        bf16* dst = (bf16*)Cout;
        if (isv == 0)
          dst[(((size_t)bh) * 256 + key) * 64 + d] = (bf16)v;                  // K [bh][key][d]
        else
          dst[32 * 256 * 64 + (((size_t)bh) * 64 + d) * 256 + key] = (bf16)v;  // V^T [bh][d][key]
      } else if constexpr (EMODE == 3) {
        ((float*)Cout)[(size_t)row * N + col] = v + bias[col];
      } else {  // EMODE 4
        ((float*)Cout)[((size_t)blockIdx.z * M + row) * N + col] = v;
      }
    }
  }
}

// ---------------- LayerNorm (sum of 8 fp32 partials + sr_b -> bf16) ----------------
__global__ void k_ln(const float* __restrict__ part, const float* __restrict__ srb,
                     const float* __restrict__ g, const float* __restrict__ bb,
                     bf16* __restrict__ out) {
  int row = blockIdx.x * 4 + (threadIdx.x >> 6);
  int lane = threadIdx.x & 63;
  size_t off = (size_t)row * 256 + lane * 4;
  float4 v = *(const float4*)&part[off];
#pragma unroll
  for (int z = 1; z < 8; z++) {
    float4 p = *(const float4*)&part[(size_t)z * 2048 * 256 + off];
    v.x += p.x; v.y += p.y; v.z += p.z; v.w += p.w;
  }
  int c = lane * 4;
  v.x += srb[c + 0]; v.y += srb[c + 1]; v.z += srb[c + 2]; v.w += srb[c + 3];
  float s = v.x + v.y + v.z + v.w;
#pragma unroll
  for (int i = 1; i < 64; i <<= 1) s += __shfl_xor(s, i, 64);
  float mu = s * (1.f / 256.f);
  float d0 = v.x - mu, d1 = v.y - mu, d2 = v.z - mu, d3 = v.w - mu;
  float q = d0 * d0 + d1 * d1 + d2 * d2 + d3 * d3;
#pragma unroll
  for (int i = 1; i < 64; i <<= 1) q += __shfl_xor(q, i, 64);
  float rs = rsqrtf(q * (1.f / 256.f) + 1e-5f);
  bf16x4 o;
  o[0] = (bf16)(d0 * rs * g[c + 0] + bb[c + 0]);
  o[1] = (bf16)(d1 * rs * g[c + 1] + bb[c + 1]);
  o[2] = (bf16)(d2 * rs * g[c + 2] + bb[c + 2]);
  o[3] = (bf16)(d3 * rs * g[c + 3] + bb[c + 3]);
  *(bf16x4*)&out[(size_t)row * 256 + c] = o;
}

// ---------------- attention: fused Q-proj, single 36.9KB LDS buffer ----------------
// grid (32 bh, 64 qtiles), block 256 (4 waves), 4 blocks/CU.
// LDS buffer (36864 B) time-multiplexed:
//   t0: wave-local Q stripe [64][72]        (C->A round-trip, no barrier)
//   t1: cooperative K stage [256][72]       (barrier-protected)
//   t2: wave-local P stripe [64][264]       (after K dead, barrier-protected)
// x, Wq, V^T MFMA fragments load directly from global (L2-hot, independent loads).
__global__ __launch_bounds__(256, 4) void k_attn(
    const bf16* __restrict__ xbf,  // [B*4096][256]
    const bf16* __restrict__ WqT,  // [256 out][256 in]
    const bf16* __restrict__ Kb,   // [32][256][64]
    const bf16* __restrict__ Vt_g, // [32][64][256]  (V^T)
    bf16* __restrict__ O) {        // [B*4096][256]
  int bh = blockIdx.x, qt = blockIdx.y;
  int b = bh >> 2, h = bh & 3;
  int tid = threadIdx.x, wave = tid >> 6, lane = tid & 63;
  int quad = lane >> 4, l16 = lane & 15;

  __shared__ alignas(16) bf16 Ls[256 * 72];  // 36864 B

  const bf16* xrow  = xbf + ((size_t)(b * 4096 + qt * 64 + wave * 16 + l16) << 8) + quad * 8;
  const bf16* wqrow = WqT + ((size_t)(h * 64) << 8);
  const bf16* Kbh   = Kb + (size_t)bh * 256 * 64;
  const bf16* Vbh   = Vt_g + (size_t)bh * 64 * 256;

  // ---- phase 1: Q = x @ Wq_head (fragments from global) ----
  f32x4 q[4];
#pragma unroll
  for (int i = 0; i < 4; i++) q[i] = (f32x4){0.f, 0.f, 0.f, 0.f};
#pragma unroll
  for (int k0 = 0; k0 < 256; k0 += 32) {
    bf16x8 ax = *(const bf16x8*)(xrow + k0);
#pragma unroll
    for (int nt = 0; nt < 4; nt++) {
      bf16x8 bw = *(const bf16x8*)&wqrow[((size_t)(nt * 16 + l16) << 8) + k0 + quad * 8];
      q[nt] = MFMA16(ax, bw, q[nt]);
    }
  }

  // Q C-layout -> wave-local stripe [64][72] in Ls (pre-K)
#pragma unroll
  for (int nt = 0; nt < 4; nt++)
#pragma unroll
    for (int r = 0; r < 4; r++)
      Ls[(wave * 16 + quad * 4 + r) * 72 + nt * 16 + l16] = (bf16)q[nt][r];
  WAIT_LDS();
  bf16x8 aq0 = *(const bf16x8*)&Ls[(wave * 16 + l16) * 72 + 0 + quad * 8];
  bf16x8 aq1 = *(const bf16x8*)&Ls[(wave * 16 + l16) * 72 + 32 + quad * 8];
  __syncthreads();  // all waves' Q readback done; Ls free for K

  // ---- cooperative K stage [256][64] -> Ls[256][72] ----
#pragma unroll
  for (int t = 0; t < 8; t++) {
    int c = tid + t * 256;
    int row = c >> 3, c8 = (c & 7) * 8;
    *(bf16x8*)&Ls[row * 72 + c8] = *(const bf16x8*)&Kbh[row * 64 + c8];
  }
  __syncthreads();  // K staged

  // ---- phase 2: S = Q K^T (K from LDS) ----
  f32x4 s[16];
#pragma unroll
  for (int i = 0; i < 16; i++) s[i] = (f32x4){0.f, 0.f, 0.f, 0.f};
#pragma unroll
  for (int nt = 0; nt < 16; nt++) {
    bf16x8 b0 = *(const bf16x8*)&Ls[(nt * 16 + l16) * 72 + 0 + quad * 8];
    bf16x8 b1 = *(const bf16x8*)&Ls[(nt * 16 + l16) * 72 + 32 + quad * 8];
    s[nt] = MFMA16(aq0, b0, s[nt]);
    s[nt] = MFMA16(aq1, b1, s[nt]);
  }

  // softmax over 256 keys; lane holds rows quad*4+r, col l16 of each 16-tile
  const float scale = 0.125f;
#pragma unroll
  for (int r = 0; r < 4; r++) {
    float m = -1e30f;
#pragma unroll
    for (int nt = 0; nt < 16; nt++) m = fmaxf(m, s[nt][r]);
#pragma unroll
    for (int i = 1; i < 16; i <<= 1) m = fmaxf(m, __shfl_xor(m, i, 64));
    float sum = 0.f;
#pragma unroll
    for (int nt = 0; nt < 16; nt++) {
      float e = __expf((s[nt][r] - m) * scale);
      s[nt][r] = e;
      sum += e;
    }
#pragma unroll
    for (int i = 1; i < 16; i <<= 1) sum += __shfl_xor(sum, i, 64);
    float inv = 1.f / sum;
#pragma unroll
    for (int nt = 0; nt < 16; nt++) s[nt][r] *= inv;
  }
  __syncthreads();  // all waves' K reads done; Ls free for P

  // P C-layout -> wave-local stripe [64][264] in Ls
#pragma unroll
  for (int nt = 0; nt < 16; nt++)
#pragma unroll
    for (int r = 0; r < 4; r++)
      Ls[(wave * 16 + quad * 4 + r) * 264 + nt * 16 + l16] = (bf16)s[nt][r];
  WAIT_LDS();

  // ---- phase 3: O = P V (P from LDS, V^T fragments from global) ----
  f32x4 o[4];
#pragma unroll
  for (int i = 0; i < 4; i++) o[i] = (f32x4){0.f, 0.f, 0.f, 0.f};
#pragma unroll
  for (int k0 = 0; k0 < 256; k0 += 32) {
    bf16x8 ap = *(const bf16x8*)&Ls[(wave * 16 + l16) * 264 + k0 + quad * 8];
#pragma unroll
    for (int nt = 0; nt < 4; nt++) {
      bf16x8 bv = *(const bf16x8*)&Vbh[(nt * 16 + l16) * 256 + k0 + quad * 8];
      o[nt] = MFMA16(ap, bv, o[nt]);
    }
  }

  size_t orow = (size_t)b * 4096 + qt * 64 + wave * 16 + quad * 4;
#pragma unroll
  for (int nt = 0; nt < 4; nt++) {
    int col = h * 64 + nt * 16 + l16;
#pragma unroll
    for (int r = 0; r < 4; r++) O[(orow + r) * 256 + col] = (bf16)o[nt][r];
  }
}

// ---------------- launch ----------------
extern "C" void kernel_launch(void* const* d_in, const int* in_sizes, int n_in,
                              void* d_out, int out_size, void* d_ws, size_t ws_size,
                              hipStream_t stream) {
  (void)in_sizes; (void)n_in; (void)out_size; (void)ws_size;
  const float* x   = (const float*)d_in[0];
  const float* Wq  = (const float*)d_in[3];
  const float* Wkv = (const float*)d_in[4];
  const float* srw = (const float*)d_in[5];
  const float* srb = (const float*)d_in[6];
  const float* lng = (const float*)d_in[7];
  const float* lnb = (const float*)d_in[8];
  const float* Wo  = (const float*)d_in[9];
  const float* bo  = (const float*)d_in[10];
  float* out = (float*)d_out;

  char* ws = (char*)d_ws;
  bf16*  x_bf  = (bf16*)(ws + 0);          // 16,777,216 B
  bf16*  AObuf = (bf16*)(ws + 16777216);   // 16,777,216
  float* convp = (float*)(ws + 33554432);  // 16,777,216 (8 partials)
  bf16*  WqT   = (bf16*)(ws + 50331648);   //    131,072
  bf16*  WkvT  = (bf16*)(ws + 50462720);   //    262,144
  bf16*  WoT   = (bf16*)(ws + 50724864);   //    131,072
  bf16*  srwT  = (bf16*)(ws + 50855936);   //  2,097,152
  bf16*  xln   = (bf16*)(ws + 52953088);   //  1,048,576
  bf16*  kvbuf = (bf16*)(ws + 54001664);   //  2,097,152 (K then V^T)

  k_prep<<<10240, 256, 0, stream>>>(x, Wq, Wkv, Wo, srw, x_bf, WqT, WkvT, WoT, srwT);
  // conv (im2col GEMM), split-K 8x512 -> fp32 partials [8][2048][256]
  k_gemm<1, 4><<<dim3(32, 4, 8), 256, 0, stream>>>(x_bf, srwT, convp, nullptr, 2048, 256, 512);
  // LayerNorm (+partial reduce +sr_b) -> bf16 [2048][256]
  k_ln<<<512, 256, 0, stream>>>(convp, srb, lng, lnb, xln);
  // KV = xln @ Wkv -> K [32][256][64], V^T [32][64][256] bf16
  k_gemm<0, 2><<<dim3(32, 8), 256, 0, stream>>>(xln, WkvT, kvbuf, nullptr, 2048, 512, 256);
  // attention (Q-proj fused, single-buffer LDS)
  k_attn<<<dim3(32, 64), 256, 0, stream>>>(x_bf, WqT, kvbuf, kvbuf + (size_t)32 * 256 * 64, AObuf);
  // out = AO @ Wo + bo -> fp32 d_out
  k_gemm<0, 3><<<dim3(512, 4), 256, 0, stream>>>(AObuf, WoT, out, bo, 32768, 256, 256);
}

// Round 6
// 196.070 us; speedup vs baseline: 1.2397x; 1.1172x over previous
//
#include <hip/hip_runtime.h>

typedef __bf16 bf16;
typedef bf16 bf16x8 __attribute__((ext_vector_type(8)));
typedef bf16 bf16x4 __attribute__((ext_vector_type(4)));
typedef float f32x4 __attribute__((ext_vector_type(4)));

#define MFMA16(a, b, c) __builtin_amdgcn_mfma_f32_16x16x32_bf16(a, b, c, 0, 0, 0)
// wait lgkmcnt(0) only (vmcnt=0x3f, expcnt=7): per-wave LDS drain, no global drain
#define WAIT_LDS() __builtin_amdgcn_s_waitcnt(0xC07F)

// ---------------- merged prep kernel ----------------
__global__ void k_prep(const float* __restrict__ x, const float* __restrict__ Wq,
                       const float* __restrict__ Wkv, const float* __restrict__ Wo,
                       const float* __restrict__ srw,
                       bf16* __restrict__ x_bf, bf16* __restrict__ WqT,
                       bf16* __restrict__ WkvT, bf16* __restrict__ WoT,
                       bf16* __restrict__ srwT) {
  int bid = blockIdx.x, tid = threadIdx.x;
  if (bid < 8192) {
    int i = (bid * 256 + tid) * 4;
    float4 v = *(const float4*)(x + i);
    bf16x4 o;
    o[0] = (bf16)v.x; o[1] = (bf16)v.y; o[2] = (bf16)v.z; o[3] = (bf16)v.w;
    *(bf16x4*)(x_bf + i) = o;
  } else if (bid < 9216) {
    int id = (bid - 8192) * 256 + tid;  // 0..262143
    if (id < 65536) {                   // WqT
      int c = id >> 8, r = id & 255;
      WqT[id] = (bf16)Wq[r * 256 + c];
    } else if (id < 196608) {           // WkvT
      int l = id - 65536;
      int c = l >> 8, r = l & 255;
      WkvT[l] = (bf16)Wkv[r * 512 + c];
    } else {                            // WoT
      int l = id - 196608;
      int c = l >> 8, r = l & 255;
      WoT[l] = (bf16)Wo[r * 256 + c];
    }
  } else {
    int id4 = ((bid - 9216) * 256 + tid) * 4;  // input-linear o*4096+i*16+p
    int o = id4 >> 12, rem = id4 & 4095;
    int i = rem >> 4, p = rem & 15;
    float4 v = *(const float4*)(srw + id4);
    srwT[(o << 12) + ((p + 0) << 8) + i] = (bf16)v.x;
    srwT[(o << 12) + ((p + 1) << 8) + i] = (bf16)v.y;
    srwT[(o << 12) + ((p + 2) << 8) + i] = (bf16)v.z;
    srwT[(o << 12) + ((p + 3) << 8) + i] = (bf16)v.w;
  }
}

// ---------------- generic MFMA GEMM (conv / KV / out) ----------------
template <int AMODE, int EMODE>
__global__ __launch_bounds__(256, 2) void k_gemm(
    const bf16* __restrict__ A, const bf16* __restrict__ Bt,
    void* __restrict__ Cout, const float* __restrict__ bias,
    int M, int N, int K) {
  constexpr int LDT = 72;
  __shared__ alignas(16) bf16 As[64 * LDT];
  __shared__ alignas(16) bf16 Bs[64 * LDT];
  int tid = threadIdx.x;
  int m0 = blockIdx.x * 64, n0 = blockIdx.y * 64;
  int kbeg = blockIdx.z * K;
  int wave = tid >> 6, lane = tid & 63;
  int quad = lane >> 4, l16 = lane & 15;

  f32x4 acc[4];
#pragma unroll
  for (int i = 0; i < 4; i++) acc[i] = (f32x4){0.f, 0.f, 0.f, 0.f};

  for (int k0 = kbeg; k0 < kbeg + K; k0 += 64) {
#pragma unroll
    for (int t = 0; t < 2; t++) {
      int c = tid + t * 256;
      int row = c >> 3, c8 = (c & 7) * 8;
      const bf16* asrc;
      if constexpr (AMODE == 0) {
        asrc = A + (size_t)(m0 + row) * K + k0 + c8;
      } else {
        int m = m0 + row;
        int b = m >> 8, tt = m & 255;
        int oh = tt >> 4, ow = tt & 15;
        int p = k0 >> 8;
        int kh = p >> 2, kw = p & 3;
        int tok = (oh * 4 + kh) * 64 + ow * 4 + kw;
        asrc = A + ((size_t)(b * 4096 + tok) << 8) + (k0 & 255) + c8;
      }
      *(bf16x8*)&As[row * LDT + c8] = *(const bf16x8*)asrc;
      *(bf16x8*)&Bs[row * LDT + c8] =
          *(const bf16x8*)(Bt + (size_t)(n0 + row) * ((AMODE == 1) ? 4096 : K) + k0 + c8);
    }
    __syncthreads();
#pragma unroll
    for (int kk = 0; kk < 64; kk += 32) {
      bf16x8 af = *(const bf16x8*)&As[(wave * 16 + l16) * LDT + kk + quad * 8];
#pragma unroll
      for (int nt = 0; nt < 4; nt++) {
        bf16x8 bfr = *(const bf16x8*)&Bs[(nt * 16 + l16) * LDT + kk + quad * 8];
        acc[nt] = MFMA16(af, bfr, acc[nt]);
      }
    }
    __syncthreads();
  }

  int rbase = m0 + wave * 16 + quad * 4;
#pragma unroll
  for (int nt = 0; nt < 4; nt++) {
    int col = n0 + nt * 16 + l16;
#pragma unroll
    for (int r = 0; r < 4; r++) {
      float v = acc[nt][r];
      int row = rbase + r;
      if constexpr (EMODE == 2) {
        int b = row >> 8, key = row & 255;
        int isv = col >> 8, c2 = col & 255;
        int hh = c2 >> 6, d = c2 & 63;
        int bh = b * 4 + hh;
        bf16* dst = (bf16*)Cout;
        if (isv == 0)
          dst[(((size_t)bh) * 256 + key) * 64 + d] = (bf16)v;                  // K [bh][key][d]
        else
          dst[32 * 256 * 64 + (((size_t)bh) * 64 + d) * 256 + key] = (bf16)v;  // V^T [bh][d][key]
      } else if constexpr (EMODE == 3) {
        ((float*)Cout)[(size_t)row * N + col] = v + bias[col];
      } else {  // EMODE 4
        ((float*)Cout)[((size_t)blockIdx.z * M + row) * N + col] = v;
      }
    }
  }
}

// ---------------- LayerNorm (sum of 8 fp32 partials + sr_b -> bf16) ----------------
__global__ void k_ln(const float* __restrict__ part, const float* __restrict__ srb,
                     const float* __restrict__ g, const float* __restrict__ bb,
                     bf16* __restrict__ out) {
  int row = blockIdx.x * 4 + (threadIdx.x >> 6);
  int lane = threadIdx.x & 63;
  size_t off = (size_t)row * 256 + lane * 4;
  float4 v = *(const float4*)&part[off];
#pragma unroll
  for (int z = 1; z < 8; z++) {
    float4 p = *(const float4*)&part[(size_t)z * 2048 * 256 + off];
    v.x += p.x; v.y += p.y; v.z += p.z; v.w += p.w;
  }
  int c = lane * 4;
  v.x += srb[c + 0]; v.y += srb[c + 1]; v.z += srb[c + 2]; v.w += srb[c + 3];
  float s = v.x + v.y + v.z + v.w;
#pragma unroll
  for (int i = 1; i < 64; i <<= 1) s += __shfl_xor(s, i, 64);
  float mu = s * (1.f / 256.f);
  float d0 = v.x - mu, d1 = v.y - mu, d2 = v.z - mu, d3 = v.w - mu;
  float q = d0 * d0 + d1 * d1 + d2 * d2 + d3 * d3;
#pragma unroll
  for (int i = 1; i < 64; i <<= 1) q += __shfl_xor(q, i, 64);
  float rs = rsqrtf(q * (1.f / 256.f) + 1e-5f);
  bf16x4 o;
  o[0] = (bf16)(d0 * rs * g[c + 0] + bb[c + 0]);
  o[1] = (bf16)(d1 * rs * g[c + 1] + bb[c + 1]);
  o[2] = (bf16)(d2 * rs * g[c + 2] + bb[c + 2]);
  o[3] = (bf16)(d3 * rs * g[c + 3] + bb[c + 3]);
  *(bf16x4*)&out[(size_t)row * 256 + c] = o;
}

// ---------------- attention: fused Q-proj, K+V in LDS, 2 barriers ----------------
// grid (64 qt, 32 bh) -- qt fastest so resident/adjacent blocks share bh
// (K/V L2-hot, Wq head slice L1-resident). Block 256 (4 waves), 2 blocks/CU.
// LDS: Ks[256][72] (P stripe [64][264] aliases it after S) | Vt[64][264] | Qs[64][72].
// Staging is issued first in program order so Q-proj compute overlaps its latency.
__global__ __launch_bounds__(256, 2) void k_attn(
    const bf16* __restrict__ xbf,  // [B*4096][256]
    const bf16* __restrict__ WqT,  // [256 out][256 in]
    const bf16* __restrict__ Kb,   // [32][256][64]
    const bf16* __restrict__ Vt_g, // [32][64][256]  (V^T)
    bf16* __restrict__ O) {        // [B*4096][256]
  int qt = blockIdx.x, bh = blockIdx.y;
  int b = bh >> 2, h = bh & 3;
  int tid = threadIdx.x, wave = tid >> 6, lane = tid & 63;
  int quad = lane >> 4, l16 = lane & 15;

  __shared__ alignas(16) bf16 Ks[256 * 72];  // 36864 B
  __shared__ alignas(16) bf16 Vt[64 * 264];  // 33792 B
  __shared__ alignas(16) bf16 Qs[64 * 72];   //  9216 B  (total 79872)

  const bf16* Kbh = Kb + (size_t)bh * 256 * 64;
  const bf16* Vbh = Vt_g + (size_t)bh * 64 * 256;

  // ---- cooperative K/V staging (issued first; linear b128 copies) ----
#pragma unroll
  for (int t = 0; t < 8; t++) {
    int c = tid + t * 256;
    *(bf16x8*)&Ks[(c >> 3) * 72 + (c & 7) * 8] = *(const bf16x8*)&Kbh[c * 8];
    *(bf16x8*)&Vt[(c >> 5) * 264 + (c & 31) * 8] = *(const bf16x8*)&Vbh[c * 8];
  }

  // ---- phase 1 (overlaps staging): Q = x @ Wq_head, fragments from global ----
  const bf16* xrow  = xbf + ((size_t)(b * 4096 + qt * 64 + wave * 16 + l16) << 8) + quad * 8;
  const bf16* wqrow = WqT + ((size_t)(h * 64) << 8);
  f32x4 q[4];
#pragma unroll
  for (int i = 0; i < 4; i++) q[i] = (f32x4){0.f, 0.f, 0.f, 0.f};
#pragma unroll
  for (int k0 = 0; k0 < 256; k0 += 32) {
    bf16x8 ax = *(const bf16x8*)(xrow + k0);
#pragma unroll
    for (int nt = 0; nt < 4; nt++) {
      bf16x8 bw = *(const bf16x8*)&wqrow[((size_t)(nt * 16 + l16) << 8) + k0 + quad * 8];
      q[nt] = MFMA16(ax, bw, q[nt]);
    }
  }

  // Q C-layout -> wave-local stripe in Qs (separate region; no barrier needed)
#pragma unroll
  for (int nt = 0; nt < 4; nt++)
#pragma unroll
    for (int r = 0; r < 4; r++)
      Qs[(wave * 16 + quad * 4 + r) * 72 + nt * 16 + l16] = (bf16)q[nt][r];
  WAIT_LDS();
  bf16x8 aq0 = *(const bf16x8*)&Qs[(wave * 16 + l16) * 72 + 0 + quad * 8];
  bf16x8 aq1 = *(const bf16x8*)&Qs[(wave * 16 + l16) * 72 + 32 + quad * 8];
  __syncthreads();  // staging complete everywhere

  // ---- phase 2: S = Q K^T (K from LDS; 16 independent chains) ----
  f32x4 s[16];
#pragma unroll
  for (int i = 0; i < 16; i++) s[i] = (f32x4){0.f, 0.f, 0.f, 0.f};
#pragma unroll
  for (int nt = 0; nt < 16; nt++) {
    bf16x8 b0 = *(const bf16x8*)&Ks[(nt * 16 + l16) * 72 + 0 + quad * 8];
    bf16x8 b1 = *(const bf16x8*)&Ks[(nt * 16 + l16) * 72 + 32 + quad * 8];
    s[nt] = MFMA16(aq0, b0, s[nt]);
    s[nt] = MFMA16(aq1, b1, s[nt]);
  }

  // softmax over 256 keys; lane holds rows quad*4+r, col l16 of each 16-tile
  const float scale = 0.125f;
#pragma unroll
  for (int r = 0; r < 4; r++) {
    float m = -1e30f;
#pragma unroll
    for (int nt = 0; nt < 16; nt++) m = fmaxf(m, s[nt][r]);
#pragma unroll
    for (int i = 1; i < 16; i <<= 1) m = fmaxf(m, __shfl_xor(m, i, 64));
    float sum = 0.f;
#pragma unroll
    for (int nt = 0; nt < 16; nt++) {
      float e = __expf((s[nt][r] - m) * scale);
      s[nt][r] = e;
      sum += e;
    }
#pragma unroll
    for (int i = 1; i < 16; i <<= 1) sum += __shfl_xor(sum, i, 64);
    float inv = 1.f / sum;
#pragma unroll
    for (int nt = 0; nt < 16; nt++) s[nt][r] *= inv;
  }
  __syncthreads();  // all waves done reading Ks; its region is free for P

  // P C-layout -> wave-local stripe [64][264] aliasing Ks region
  bf16* Ps = Ks;
#pragma unroll
  for (int nt = 0; nt < 16; nt++)
#pragma unroll
    for (int r = 0; r < 4; r++)
      Ps[(wave * 16 + quad * 4 + r) * 264 + nt * 16 + l16] = (bf16)s[nt][r];
  WAIT_LDS();

  // ---- phase 3: O = P V (both operands from LDS) ----
  f32x4 o[4];
#pragma unroll
  for (int i = 0; i < 4; i++) o[i] = (f32x4){0.f, 0.f, 0.f, 0.f};
#pragma unroll
  for (int k0 = 0; k0 < 256; k0 += 32) {
    bf16x8 ap = *(const bf16x8*)&Ps[(wave * 16 + l16) * 264 + k0 + quad * 8];
#pragma unroll
    for (int nt = 0; nt < 4; nt++) {
      bf16x8 bv = *(const bf16x8*)&Vt[(nt * 16 + l16) * 264 + k0 + quad * 8];
      o[nt] = MFMA16(ap, bv, o[nt]);
    }
  }

  size_t orow = (size_t)b * 4096 + qt * 64 + wave * 16 + quad * 4;
#pragma unroll
  for (int nt = 0; nt < 4; nt++) {
    int col = h * 64 + nt * 16 + l16;
#pragma unroll
    for (int r = 0; r < 4; r++) O[(orow + r) * 256 + col] = (bf16)o[nt][r];
  }
}

// ---------------- launch ----------------
extern "C" void kernel_launch(void* const* d_in, const int* in_sizes, int n_in,
                              void* d_out, int out_size, void* d_ws, size_t ws_size,
                              hipStream_t stream) {
  (void)in_sizes; (void)n_in; (void)out_size; (void)ws_size;
  const float* x   = (const float*)d_in[0];
  const float* Wq  = (const float*)d_in[3];
  const float* Wkv = (const float*)d_in[4];
  const float* srw = (const float*)d_in[5];
  const float* srb = (const float*)d_in[6];
  const float* lng = (const float*)d_in[7];
  const float* lnb = (const float*)d_in[8];
  const float* Wo  = (const float*)d_in[9];
  const float* bo  = (const float*)d_in[10];
  float* out = (float*)d_out;

  char* ws = (char*)d_ws;
  bf16*  x_bf  = (bf16*)(ws + 0);          // 16,777,216 B
  bf16*  AObuf = (bf16*)(ws + 16777216);   // 16,777,216
  float* convp = (float*)(ws + 33554432);  // 16,777,216 (8 partials)
  bf16*  WqT   = (bf16*)(ws + 50331648);   //    131,072
  bf16*  WkvT  = (bf16*)(ws + 50462720);   //    262,144
  bf16*  WoT   = (bf16*)(ws + 50724864);   //    131,072
  bf16*  srwT  = (bf16*)(ws + 50855936);   //  2,097,152
  bf16*  xln   = (bf16*)(ws + 52953088);   //  1,048,576
  bf16*  kvbuf = (bf16*)(ws + 54001664);   //  2,097,152 (K then V^T)

  k_prep<<<10240, 256, 0, stream>>>(x, Wq, Wkv, Wo, srw, x_bf, WqT, WkvT, WoT, srwT);
  // conv (im2col GEMM), split-K 8x512 -> fp32 partials [8][2048][256]
  k_gemm<1, 4><<<dim3(32, 4, 8), 256, 0, stream>>>(x_bf, srwT, convp, nullptr, 2048, 256, 512);
  // LayerNorm (+partial reduce +sr_b) -> bf16 [2048][256]
  k_ln<<<512, 256, 0, stream>>>(convp, srb, lng, lnb, xln);
  // KV = xln @ Wkv -> K [32][256][64], V^T [32][64][256] bf16
  k_gemm<0, 2><<<dim3(32, 8), 256, 0, stream>>>(xln, WkvT, kvbuf, nullptr, 2048, 512, 256);
  // attention (Q-proj fused; K,V LDS-staged; qt-fastest grid for locality)
  k_attn<<<dim3(64, 32), 256, 0, stream>>>(x_bf, WqT, kvbuf, kvbuf + (size_t)32 * 256 * 64, AObuf);
  // out = AO @ Wo + bo -> fp32 d_out
  k_gemm<0, 3><<<dim3(512, 4), 256, 0, stream>>>(AObuf, WoT, out, bo, 32768, 256, 256);
}